// Round 9
// baseline (7826.917 us; speedup 1.0000x reference)
//
#include <hip/hip_runtime.h>

typedef unsigned short u16;
typedef unsigned int   u32;
typedef unsigned long long u64;
typedef __attribute__((ext_vector_type(8))) __bf16 bf16x8;
typedef __attribute__((ext_vector_type(4))) float  f32x4;

#define NWG    128
#define TSTEPS 512

// ---------------- helpers ----------------
__device__ __forceinline__ u16 f2bf(float f) {
  union { float f; u32 u; } v; v.f = f;
  return (u16)((v.u + 0x7FFFu + ((v.u >> 16) & 1u)) >> 16);  // RNE
}
__device__ __forceinline__ float sigf(float x)     { return 1.f / (1.f + __expf(-x)); }
__device__ __forceinline__ float tanhfast(float x) { return 2.f / (1.f + __expf(-2.f * x)) - 1.f; }

// fp32 -> bf16 bulk convert (x only; h0 uses the tiled converter below)
__global__ void convert_x_kernel(const float* __restrict__ x, u16* __restrict__ xb, long n) {
  long i = (long)(blockIdx.x * blockDim.x + threadIdx.x) * 4;
  long stride = (long)gridDim.x * blockDim.x * 4;
  for (; i < n; i += stride) {
    float4 v = *reinterpret_cast<const float4*>(x + i);
    ushort4 o; o.x = f2bf(v.x); o.y = f2bf(v.y); o.z = f2bf(v.z); o.w = f2bf(v.w);
    *reinterpret_cast<ushort4*>(xb + i) = o;
  }
}

// h tiled layout (1KB tiles, matches the MFMA A-fragment gather exactly):
//   tile_m = row>>4, tile_k = k>>5, elem = (tile_m*32 + tile_k)*512
//                                        + (row&15)*32 + ((k>>3)&3)*8 + (k&7)
__global__ void convert_h0_tiled(const float* __restrict__ h0, u16* __restrict__ hb) {
  int gid = blockIdx.x * blockDim.x + threadIdx.x;   // 32768 u32 units (2 elems each)
  int row = gid >> 9;
  int k0  = (gid & 511) << 1;
  float a = h0[row * 1024 + k0];
  float b = h0[row * 1024 + k0 + 1];
  int off = ((row >> 4) * 32 + (k0 >> 5)) * 512 + (row & 15) * 32 + ((k0 >> 3) & 3) * 8 + (k0 & 7);
  u32 hv = (u32)f2bf(a) | ((u32)f2bf(b) << 16);
  *((u32*)hb + (off >> 1)) = hv;
}

// Gather W into exact per-(wg,wave,ks,tile,lane) MFMA B-fragment order, bf16.
// (identical to the R1/R4/R6/R7/R8 PASSING version)
__global__ void arrange_w_kernel(const float* __restrict__ Wf, const float* __restrict__ Wi,
                                 const float* __restrict__ Wc, const float* __restrict__ Wo,
                                 u16* __restrict__ wfrag) {
  __shared__ float lds[4][512][8];
  const int n = blockIdx.x >> 2;      // 0..127
  const int w = blockIdx.x & 3;       // 0..3
  const int tid = threadIdx.x;
  #pragma unroll
  for (int g = 0; g < 4; ++g) {
    const float* W = (g == 0) ? Wf : (g == 1) ? Wi : (g == 2) ? Wc : Wo;
    for (int it = 0; it < 16; ++it) {
      int e = it * 256 + tid;
      int kk = e >> 3, jj = e & 7;
      lds[g][kk][jj] = W[(size_t)(w * 512 + kk) * 1024 + n * 8 + jj];
    }
  }
  __syncthreads();
  u16* outp = wfrag + ((size_t)blockIdx.x << 14);   // 16384 elems per (n,w)
  for (int it = 0; it < 64; ++it) {
    int e = it * 256 + tid;
    int b = e & 7, lane = (e >> 3) & 63, tile = (e >> 9) & 1, ks = e >> 10;
    int kk = ks * 32 + ((lane >> 4) << 3) + b;
    int c  = tile * 16 + (lane & 15);
    int g  = c >> 3, jj = c & 7;
    outp[e] = f2bf(lds[g][kk][jj]);
  }
}

// Persistent LSTM: 128 WGs x 256 thr. WG n owns j in [8n, 8n+8) (32 gate-cols).
// R9 = R8 data path (tiled h, zero cache maintenance) + SHORT PUBLISH CHAIN:
//   - no aggregator: producers atomicAdd(cnt,1) fire-and-forget; w0 polls cnt.
//   - per-wave vmcnt(0) drain of the h store + LDS done[] signal; wave 3's
//     lane0 collects and fires the add (no full end-of-step barrier).
//   - out stores issued AFTER publish (their ack is off the critical path).
//   - part[] double-buffered by t-parity so x-waves roll into t+1 early.
__launch_bounds__(256, 1)
__global__ void lstm_main_kernel(
    const u16* __restrict__ xbf, const u16* __restrict__ wfrag,
    const float* __restrict__ c0,
    const float* __restrict__ bF, const float* __restrict__ bI,
    const float* __restrict__ bC, const float* __restrict__ bO,
    u16* __restrict__ hb, float* __restrict__ out, u32* flags)
{
  const int n    = blockIdx.x;
  const int tid  = threadIdx.x;
  const int w    = tid >> 6;
  const int lane = tid & 63;
  const int lr   = lane & 15;
  const int hi   = lane >> 4;
  const int lk   = hi << 3;
  u32* const cnt = flags;             // single global step counter

  __shared__ float part[2][4][64][36];  // t-parity double-buffered K-split partials
  __shared__ u32 done[4];               // per-wave h-store-acked signal (monotonic)
  __shared__ u32 go;                    // wave0 -> wave1 step release

  // persistent B fragments (W) — loaded once, live in registers across all steps
  bf16x8 bq[16][2];
  {
    const u16* wp = wfrag + ((size_t)(n * 4 + w) << 14) + lane * 8;
    #pragma unroll
    for (int ks = 0; ks < 16; ++ks) {
      bq[ks][0] = *reinterpret_cast<const bf16x8*>(wp + ks * 1024);
      bq[ks][1] = *reinterpret_cast<const bf16x8*>(wp + ks * 1024 + 512);
    }
  }
  if (tid < 4) done[tid] = 0;
  if (tid == 0) go = 0;

  // elementwise ownership: thread -> (row, jj0=even jj), c-state in fp32 registers
  const int erow = tid >> 2;
  const int ejj  = (tid & 3) << 1;
  const int j0   = n * 8 + ejj;
  float cR0 = c0[erow * 1024 + j0];
  float cR1 = c0[erow * 1024 + j0 + 1];
  const float bf0 = bF[j0], bf1 = bF[j0 + 1];
  const float bi0 = bI[j0], bi1 = bI[j0 + 1];
  const float bc0 = bC[j0], bc1 = bC[j0 + 1];
  const float bo0 = bO[j0], bo1 = bO[j0 + 1];
  // tiled h-store offset (constant per thread): row=erow, k=j0 (j0 even)
  const int hoff_u32 = (((erow >> 4) * 32 + (j0 >> 5)) * 512
                        + (erow & 15) * 32 + ((j0 >> 3) & 3) * 8 + (j0 & 7)) >> 1;
  __syncthreads();

  #pragma unroll 1
  for (int t = 0; t < TSTEPS; ++t) {
    const int par = t & 1;
    f32x4 acc[4][2];
    #pragma unroll
    for (int m = 0; m < 4; ++m) {
      acc[m][0] = (f32x4){0.f, 0.f, 0.f, 0.f};
      acc[m][1] = (f32x4){0.f, 0.f, 0.f, 0.f};
    }

    if (w < 2) {
      // ---- wait for step-(t-1) h: w0 polls global cnt; w1 waits on LDS go ----
      if (t > 0) {
        const u32 need = (u32)t * (u32)NWG;
        if (w == 0) {
          while (__hip_atomic_load(cnt, __ATOMIC_RELAXED, __HIP_MEMORY_SCOPE_AGENT) < need)
            __builtin_amdgcn_s_sleep(2);
          if (lane == 0)
            __hip_atomic_store(&go, (u32)t, __ATOMIC_RELAXED, __HIP_MEMORY_SCOPE_WORKGROUP);
        } else {
          while (__hip_atomic_load(&go, __ATOMIC_RELAXED, __HIP_MEMORY_SCOPE_WORKGROUP) < (u32)t)
            __builtin_amdgcn_s_sleep(1);
        }
      }
      // h loads from TILED buffer: lane (lr,hi) reads u64s at tile*128 + lr*8 + hi*2
      const u64* hq = (const u64*)(hb + par * 65536);
      #pragma unroll
      for (int m = 0; m < 4; ++m) {
        union { u64 q[2]; bf16x8 v; } av[16];
        #pragma unroll
        for (int ks = 0; ks < 16; ++ks) {
          int idx = (m * 32 + w * 16 + ks) * 128 + lr * 8 + hi * 2;
          av[ks].q[0] = __hip_atomic_load(hq + idx,     __ATOMIC_RELAXED, __HIP_MEMORY_SCOPE_AGENT);
          av[ks].q[1] = __hip_atomic_load(hq + idx + 1, __ATOMIC_RELAXED, __HIP_MEMORY_SCOPE_AGENT);
        }
        #pragma unroll
        for (int ks = 0; ks < 16; ++ks) {
          acc[m][0] = __builtin_amdgcn_mfma_f32_16x16x32_bf16(av[ks].v, bq[ks][0], acc[m][0], 0, 0, 0);
          acc[m][1] = __builtin_amdgcn_mfma_f32_16x16x32_bf16(av[ks].v, bq[ks][1], acc[m][1], 0, 0, 0);
        }
      }
    } else {
      // ---- x waves: independent of h_t — plain cached loads, start immediately ----
      const u16* asrc = xbf + (size_t)t * 65536 + (w - 2) * 512;
      #pragma unroll
      for (int ks = 0; ks < 16; ++ks) {
        #pragma unroll
        for (int m = 0; m < 4; ++m) {
          bf16x8 av = *reinterpret_cast<const bf16x8*>(asrc + (m * 16 + lr) * 1024 + ks * 32 + lk);
          acc[m][0] = __builtin_amdgcn_mfma_f32_16x16x32_bf16(av, bq[ks][0], acc[m][0], 0, 0, 0);
          acc[m][1] = __builtin_amdgcn_mfma_f32_16x16x32_bf16(av, bq[ks][1], acc[m][1], 0, 0, 0);
        }
      }
    }

    // write K-split partials: D row = m*16 + hi*4 + r, col = nt*16 + lr
    #pragma unroll
    for (int m = 0; m < 4; ++m)
      #pragma unroll
      for (int nt = 0; nt < 2; ++nt)
        #pragma unroll
        for (int r = 0; r < 4; ++r)
          part[par][w][m * 16 + (hi << 2) + r][nt * 16 + lr] = acc[m][nt][r];

    __syncthreads();   // the ONLY barrier per step: partials(t) visible to all

    // reduce 4 partials + bias + gates + state update (2 elems per thread)
    float a8[8];
    #pragma unroll
    for (int q = 0; q < 2; ++q) {
      int jj = ejj + q;
      #pragma unroll
      for (int g = 0; g < 4; ++g)
        a8[q * 4 + g] = part[par][0][erow][g * 8 + jj] + part[par][1][erow][g * 8 + jj]
                      + part[par][2][erow][g * 8 + jj] + part[par][3][erow][g * 8 + jj];
    }
    float fA = sigf(a8[0] + bf0), iA = sigf(a8[1] + bi0);
    float gA = tanhfast(a8[2] + bc0), oA = sigf(a8[3] + bo0);
    float cn0 = fA * cR0 + iA * gA;
    float hn0 = oA * tanhfast(cn0);
    cR0 = cn0;
    float fB = sigf(a8[4] + bf1), iB = sigf(a8[5] + bi1);
    float gB = tanhfast(a8[6] + bc1), oB = sigf(a8[7] + bo1);
    float cn1 = fB * cR1 + iB * gB;
    float hn1 = oB * tanhfast(cn1);
    cR1 = cn1;

    // h exchange: relaxed agent atomic u32 store into the TILED buffer (parity par^1)
    {
      u32 hv = (u32)f2bf(hn0) | ((u32)f2bf(hn1) << 16);
      u32* hdst32 = (u32*)(hb + (par ^ 1) * 65536) + hoff_u32;
      __hip_atomic_store(hdst32, hv, __ATOMIC_RELAXED, __HIP_MEMORY_SCOPE_AGENT);
    }

    if (t < TSTEPS - 1) {
      // publish at the earliest instant: per-wave drain of the h store only
      asm volatile("s_waitcnt vmcnt(0)" ::: "memory");
      __builtin_amdgcn_sched_barrier(0);
      if (lane == 0)
        __hip_atomic_store(&done[w], (u32)(t + 1), __ATOMIC_RELAXED, __HIP_MEMORY_SCOPE_WORKGROUP);
      if (w == 3 && lane == 0) {
        const u32 tv = (u32)(t + 1);
        while (__hip_atomic_load(&done[0], __ATOMIC_RELAXED, __HIP_MEMORY_SCOPE_WORKGROUP) < tv ||
               __hip_atomic_load(&done[1], __ATOMIC_RELAXED, __HIP_MEMORY_SCOPE_WORKGROUP) < tv ||
               __hip_atomic_load(&done[2], __ATOMIC_RELAXED, __HIP_MEMORY_SCOPE_WORKGROUP) < tv)
          ;
        __hip_atomic_fetch_add(cnt, 1u, __ATOMIC_RELAXED, __HIP_MEMORY_SCOPE_AGENT);
      }
    }

    // fp32 outputs AFTER publish — their ack is off the critical path
    size_t ob = (size_t)t * 65536 + erow * 1024 + j0;
    out[ob]     = hn0;
    out[ob + 1] = hn1;
    if (t == TSTEPS - 1) {
      out[33554432 + erow * 1024 + j0]     = hn0;   // h_last
      out[33554432 + erow * 1024 + j0 + 1] = hn1;
      out[33619968 + erow * 1024 + j0]     = cn0;   // c_last
      out[33619968 + erow * 1024 + j0 + 1] = cn1;
    }
  }
}

extern "C" void kernel_launch(void* const* d_in, const int* in_sizes, int n_in,
                              void* d_out, int out_size, void* d_ws, size_t ws_size,
                              hipStream_t stream) {
  const float* x  = (const float*)d_in[0];
  const float* h0 = (const float*)d_in[1];
  const float* c0 = (const float*)d_in[2];
  const float* Wf = (const float*)d_in[3];
  const float* bf = (const float*)d_in[4];
  const float* Wi = (const float*)d_in[5];
  const float* bi = (const float*)d_in[6];
  const float* Wc = (const float*)d_in[7];
  const float* bc = (const float*)d_in[8];
  const float* Wo = (const float*)d_in[9];
  const float* bo = (const float*)d_in[10];

  // workspace layout: wfrag 16MB | xbf 64MB | hb 256KB | cnt 1KB
  if (ws_size < ((80u << 20) + (1u << 18) + 1024)) return;
  char* ws   = (char*)d_ws;
  u16* wfrag = (u16*)ws;
  u16* xbf   = (u16*)(ws + (16u << 20));
  u16* hb    = (u16*)(ws + (80u << 20));
  u32* flags = (u32*)(ws + (80u << 20) + (1u << 18));
  float* outp = (float*)d_out;

  hipMemsetAsync(flags, 0, 1024, stream);
  convert_x_kernel<<<2048, 256, 0, stream>>>(x, xbf, (long)512 * 64 * 1024);
  convert_h0_tiled<<<128, 256, 0, stream>>>(h0, hb);
  arrange_w_kernel<<<512, 256, 0, stream>>>(Wf, Wi, Wc, Wo, wfrag);

  void* args[] = {(void*)&xbf, (void*)&wfrag, (void*)&c0, (void*)&bf, (void*)&bi,
                  (void*)&bc, (void*)&bo, (void*)&hb, (void*)&outp, (void*)&flags};
  hipError_t e = hipLaunchCooperativeKernel((const void*)lstm_main_kernel, dim3(NWG),
                                            dim3(256), args, 0, stream);
  if (e != hipSuccess) {
    // 128 WGs at 1 WG/CU on 256 CUs are trivially co-resident; plain launch is
    // a safe fallback so a silent cooperative-launch failure can't stub the run.
    lstm_main_kernel<<<dim3(NWG), dim3(256), 0, stream>>>(xbf, wfrag, c0, bf, bi,
                                                          bc, bo, hb, outp, flags);
  }
}

// Round 10
// 5347.618 us; speedup vs baseline: 1.4636x; 1.4636x over previous
//
#include <hip/hip_runtime.h>

typedef unsigned short u16;
typedef unsigned int   u32;
typedef unsigned long long u64;
typedef __attribute__((ext_vector_type(8))) __bf16 bf16x8;
typedef __attribute__((ext_vector_type(4))) float  f32x4;

#define NWG    128
#define TSTEPS 512

// ---------------- helpers ----------------
__device__ __forceinline__ u16 f2bf(float f) {
  union { float f; u32 u; } v; v.f = f;
  return (u16)((v.u + 0x7FFFu + ((v.u >> 16) & 1u)) >> 16);  // RNE
}
__device__ __forceinline__ float sigf(float x)     { return 1.f / (1.f + __expf(-x)); }
__device__ __forceinline__ float tanhfast(float x) { return 2.f / (1.f + __expf(-2.f * x)) - 1.f; }

// fp32 -> bf16 bulk convert (x only; h0 uses the tiled converter below)
__global__ void convert_x_kernel(const float* __restrict__ x, u16* __restrict__ xb, long n) {
  long i = (long)(blockIdx.x * blockDim.x + threadIdx.x) * 4;
  long stride = (long)gridDim.x * blockDim.x * 4;
  for (; i < n; i += stride) {
    float4 v = *reinterpret_cast<const float4*>(x + i);
    ushort4 o; o.x = f2bf(v.x); o.y = f2bf(v.y); o.z = f2bf(v.z); o.w = f2bf(v.w);
    *reinterpret_cast<ushort4*>(xb + i) = o;
  }
}

// h tiled layout (1KB tiles, matches the MFMA A-fragment gather exactly):
//   tile_m = row>>4, tile_k = k>>5, elem = (tile_m*32 + tile_k)*512
//                                        + (row&15)*32 + ((k>>3)&3)*8 + (k&7)
__global__ void convert_h0_tiled(const float* __restrict__ h0, u16* __restrict__ hb) {
  int gid = blockIdx.x * blockDim.x + threadIdx.x;   // 32768 u32 units (2 elems each)
  int row = gid >> 9;
  int k0  = (gid & 511) << 1;
  float a = h0[row * 1024 + k0];
  float b = h0[row * 1024 + k0 + 1];
  int off = ((row >> 4) * 32 + (k0 >> 5)) * 512 + (row & 15) * 32 + ((k0 >> 3) & 3) * 8 + (k0 & 7);
  u32 hv = (u32)f2bf(a) | ((u32)f2bf(b) << 16);
  *((u32*)hb + (off >> 1)) = hv;
}

// Gather W into exact per-(wg,wave,ks,tile,lane) MFMA B-fragment order, bf16.
// (identical to the R1/R4/R6/R7/R8 PASSING version)
__global__ void arrange_w_kernel(const float* __restrict__ Wf, const float* __restrict__ Wi,
                                 const float* __restrict__ Wc, const float* __restrict__ Wo,
                                 u16* __restrict__ wfrag) {
  __shared__ float lds[4][512][8];
  const int n = blockIdx.x >> 2;      // 0..127
  const int w = blockIdx.x & 3;       // 0..3
  const int tid = threadIdx.x;
  #pragma unroll
  for (int g = 0; g < 4; ++g) {
    const float* W = (g == 0) ? Wf : (g == 1) ? Wi : (g == 2) ? Wc : Wo;
    for (int it = 0; it < 16; ++it) {
      int e = it * 256 + tid;
      int kk = e >> 3, jj = e & 7;
      lds[g][kk][jj] = W[(size_t)(w * 512 + kk) * 1024 + n * 8 + jj];
    }
  }
  __syncthreads();
  u16* outp = wfrag + ((size_t)blockIdx.x << 14);   // 16384 elems per (n,w)
  for (int it = 0; it < 64; ++it) {
    int e = it * 256 + tid;
    int b = e & 7, lane = (e >> 3) & 63, tile = (e >> 9) & 1, ks = e >> 10;
    int kk = ks * 32 + ((lane >> 4) << 3) + b;
    int c  = tile * 16 + (lane & 15);
    int g  = c >> 3, jj = c & 7;
    outp[e] = f2bf(lds[g][kk][jj]);
  }
}

// Persistent LSTM: 128 worker WGs + 1 aggregator WG, 256 thr each.
// R10 = R8 structure (per-WG flag stores -> aggregator -> epoch; two barriers)
//   + all 128 h-loads issued upfront (MALL latency paid once, not 4x)
//   + out stores issued AFTER the flag store (ack off the critical path)
//   + epoch replicated on 8 lines (16 pollers/line instead of 128).
__launch_bounds__(256, 1)
__global__ void lstm_main_kernel(
    const u16* __restrict__ xbf, const u16* __restrict__ wfrag,
    const float* __restrict__ c0,
    const float* __restrict__ bF, const float* __restrict__ bI,
    const float* __restrict__ bC, const float* __restrict__ bO,
    u16* __restrict__ hb, float* __restrict__ out, u32* flags)
{
  const int n    = blockIdx.x;
  const int tid  = threadIdx.x;

  // ---------------- aggregator WG: turn 128 flags into 8 epoch copies --------
  if (n == NWG) {
    if (tid < 64) {
      for (u32 tv = 1; tv < TSTEPS; ++tv) {
        while (true) {
          u32 f0 = __hip_atomic_load(flags + tid,      __ATOMIC_RELAXED, __HIP_MEMORY_SCOPE_AGENT);
          u32 f1 = __hip_atomic_load(flags + 64 + tid, __ATOMIC_RELAXED, __HIP_MEMORY_SCOPE_AGENT);
          if (__all((f0 >= tv) && (f1 >= tv))) break;
          __builtin_amdgcn_s_sleep(1);
        }
        if (tid < 8)
          __hip_atomic_store(flags + 192 + tid * 16, tv, __ATOMIC_RELAXED, __HIP_MEMORY_SCOPE_AGENT);
      }
    }
    return;
  }

  const int w    = tid >> 6;
  const int lane = tid & 63;
  const int lr   = lane & 15;
  const int hi   = lane >> 4;
  const int lk   = hi << 3;
  u32* const epoch = flags + 192 + (n & 7) * 16;   // this WG's epoch copy

  __shared__ float part[4][64][36];   // K-split partials, stride 36
  __shared__ u32 go;                  // wave0 -> wave1 step release (LDS only)

  // persistent B fragments (W) — loaded once, live in registers across all steps
  bf16x8 bq[16][2];
  {
    const u16* wp = wfrag + ((size_t)(n * 4 + w) << 14) + lane * 8;
    #pragma unroll
    for (int ks = 0; ks < 16; ++ks) {
      bq[ks][0] = *reinterpret_cast<const bf16x8*>(wp + ks * 1024);
      bq[ks][1] = *reinterpret_cast<const bf16x8*>(wp + ks * 1024 + 512);
    }
  }
  if (tid == 0) go = 0;
  __syncthreads();

  // elementwise ownership: thread -> (row, jj0=even jj), c-state in fp32 registers
  const int erow = tid >> 2;
  const int ejj  = (tid & 3) << 1;
  const int j0   = n * 8 + ejj;
  float cR0 = c0[erow * 1024 + j0];
  float cR1 = c0[erow * 1024 + j0 + 1];
  const float bf0 = bF[j0], bf1 = bF[j0 + 1];
  const float bi0 = bI[j0], bi1 = bI[j0 + 1];
  const float bc0 = bC[j0], bc1 = bC[j0 + 1];
  const float bo0 = bO[j0], bo1 = bO[j0 + 1];
  // tiled h-store offset (constant per thread): row=erow, k=j0 (j0 even)
  const int hoff_u32 = (((erow >> 4) * 32 + (j0 >> 5)) * 512
                        + (erow & 15) * 32 + ((j0 >> 3) & 3) * 8 + (j0 & 7)) >> 1;

  #pragma unroll 1
  for (int t = 0; t < TSTEPS; ++t) {
    f32x4 acc[4][2];
    #pragma unroll
    for (int m = 0; m < 4; ++m) {
      acc[m][0] = (f32x4){0.f, 0.f, 0.f, 0.f};
      acc[m][1] = (f32x4){0.f, 0.f, 0.f, 0.f};
    }

    if (w < 2) {
      // ---- wait for step-(t-1) h: w0 polls its epoch copy; w1 waits on LDS ----
      if (t > 0) {
        const u32 tv = (u32)t;
        if (w == 0) {
          while (__hip_atomic_load(epoch, __ATOMIC_RELAXED, __HIP_MEMORY_SCOPE_AGENT) < tv)
            __builtin_amdgcn_s_sleep(4);
          if (lane == 0)
            __hip_atomic_store(&go, tv, __ATOMIC_RELAXED, __HIP_MEMORY_SCOPE_WORKGROUP);
        } else {
          while (__hip_atomic_load(&go, __ATOMIC_RELAXED, __HIP_MEMORY_SCOPE_WORKGROUP) < tv)
            __builtin_amdgcn_s_sleep(1);
        }
      }
      // ---- issue ALL 128 h loads upfront (independent; latency paid once) ----
      const u64* hq = (const u64*)(hb + (t & 1) * 65536);
      union U { u64 q[2]; bf16x8 v; };
      U av0[16], av1[16], av2[16], av3[16];
      #pragma unroll
      for (int ks = 0; ks < 16; ++ks) {
        int idx = (0 * 32 + w * 16 + ks) * 128 + lr * 8 + hi * 2;
        av0[ks].q[0] = __hip_atomic_load(hq + idx,     __ATOMIC_RELAXED, __HIP_MEMORY_SCOPE_AGENT);
        av0[ks].q[1] = __hip_atomic_load(hq + idx + 1, __ATOMIC_RELAXED, __HIP_MEMORY_SCOPE_AGENT);
      }
      #pragma unroll
      for (int ks = 0; ks < 16; ++ks) {
        int idx = (1 * 32 + w * 16 + ks) * 128 + lr * 8 + hi * 2;
        av1[ks].q[0] = __hip_atomic_load(hq + idx,     __ATOMIC_RELAXED, __HIP_MEMORY_SCOPE_AGENT);
        av1[ks].q[1] = __hip_atomic_load(hq + idx + 1, __ATOMIC_RELAXED, __HIP_MEMORY_SCOPE_AGENT);
      }
      #pragma unroll
      for (int ks = 0; ks < 16; ++ks) {
        int idx = (2 * 32 + w * 16 + ks) * 128 + lr * 8 + hi * 2;
        av2[ks].q[0] = __hip_atomic_load(hq + idx,     __ATOMIC_RELAXED, __HIP_MEMORY_SCOPE_AGENT);
        av2[ks].q[1] = __hip_atomic_load(hq + idx + 1, __ATOMIC_RELAXED, __HIP_MEMORY_SCOPE_AGENT);
      }
      #pragma unroll
      for (int ks = 0; ks < 16; ++ks) {
        int idx = (3 * 32 + w * 16 + ks) * 128 + lr * 8 + hi * 2;
        av3[ks].q[0] = __hip_atomic_load(hq + idx,     __ATOMIC_RELAXED, __HIP_MEMORY_SCOPE_AGENT);
        av3[ks].q[1] = __hip_atomic_load(hq + idx + 1, __ATOMIC_RELAXED, __HIP_MEMORY_SCOPE_AGENT);
      }
      // ---- MFMAs consume in arrival order ----
      #pragma unroll
      for (int ks = 0; ks < 16; ++ks) {
        acc[0][0] = __builtin_amdgcn_mfma_f32_16x16x32_bf16(av0[ks].v, bq[ks][0], acc[0][0], 0, 0, 0);
        acc[0][1] = __builtin_amdgcn_mfma_f32_16x16x32_bf16(av0[ks].v, bq[ks][1], acc[0][1], 0, 0, 0);
      }
      #pragma unroll
      for (int ks = 0; ks < 16; ++ks) {
        acc[1][0] = __builtin_amdgcn_mfma_f32_16x16x32_bf16(av1[ks].v, bq[ks][0], acc[1][0], 0, 0, 0);
        acc[1][1] = __builtin_amdgcn_mfma_f32_16x16x32_bf16(av1[ks].v, bq[ks][1], acc[1][1], 0, 0, 0);
      }
      #pragma unroll
      for (int ks = 0; ks < 16; ++ks) {
        acc[2][0] = __builtin_amdgcn_mfma_f32_16x16x32_bf16(av2[ks].v, bq[ks][0], acc[2][0], 0, 0, 0);
        acc[2][1] = __builtin_amdgcn_mfma_f32_16x16x32_bf16(av2[ks].v, bq[ks][1], acc[2][1], 0, 0, 0);
      }
      #pragma unroll
      for (int ks = 0; ks < 16; ++ks) {
        acc[3][0] = __builtin_amdgcn_mfma_f32_16x16x32_bf16(av3[ks].v, bq[ks][0], acc[3][0], 0, 0, 0);
        acc[3][1] = __builtin_amdgcn_mfma_f32_16x16x32_bf16(av3[ks].v, bq[ks][1], acc[3][1], 0, 0, 0);
      }
    } else {
      // ---- x waves: independent of h_t — plain cached loads, start immediately ----
      const u16* asrc = xbf + (size_t)t * 65536 + (w - 2) * 512;
      #pragma unroll
      for (int ks = 0; ks < 16; ++ks) {
        #pragma unroll
        for (int m = 0; m < 4; ++m) {
          bf16x8 av = *reinterpret_cast<const bf16x8*>(asrc + (m * 16 + lr) * 1024 + ks * 32 + lk);
          acc[m][0] = __builtin_amdgcn_mfma_f32_16x16x32_bf16(av, bq[ks][0], acc[m][0], 0, 0, 0);
          acc[m][1] = __builtin_amdgcn_mfma_f32_16x16x32_bf16(av, bq[ks][1], acc[m][1], 0, 0, 0);
        }
      }
    }

    // write K-split partials: D row = m*16 + hi*4 + r, col = nt*16 + lr
    #pragma unroll
    for (int m = 0; m < 4; ++m)
      #pragma unroll
      for (int nt = 0; nt < 2; ++nt)
        #pragma unroll
        for (int r = 0; r < 4; ++r)
          part[w][m * 16 + (hi << 2) + r][nt * 16 + lr] = acc[m][nt][r];

    __syncthreads();   // barrier 1: partials visible

    // reduce 4 partials + bias + gates + state update (2 elems per thread)
    float a8[8];
    #pragma unroll
    for (int q = 0; q < 2; ++q) {
      int jj = ejj + q;
      #pragma unroll
      for (int g = 0; g < 4; ++g)
        a8[q * 4 + g] = part[0][erow][g * 8 + jj] + part[1][erow][g * 8 + jj]
                      + part[2][erow][g * 8 + jj] + part[3][erow][g * 8 + jj];
    }
    float fA = sigf(a8[0] + bf0), iA = sigf(a8[1] + bi0);
    float gA = tanhfast(a8[2] + bc0), oA = sigf(a8[3] + bo0);
    float cn0 = fA * cR0 + iA * gA;
    float hn0 = oA * tanhfast(cn0);
    cR0 = cn0;
    float fB = sigf(a8[4] + bf1), iB = sigf(a8[5] + bi1);
    float gB = tanhfast(a8[6] + bc1), oB = sigf(a8[7] + bo1);
    float cn1 = fB * cR1 + iB * gB;
    float hn1 = oB * tanhfast(cn1);
    cR1 = cn1;

    // h exchange: relaxed agent atomic u32 store into the TILED buffer
    {
      u32 hv = (u32)f2bf(hn0) | ((u32)f2bf(hn1) << 16);
      u32* hdst32 = (u32*)(hb + ((t + 1) & 1) * 65536) + hoff_u32;
      __hip_atomic_store(hdst32, hv, __ATOMIC_RELAXED, __HIP_MEMORY_SCOPE_AGENT);
    }

    // barrier 2 drains ONLY the h stores (out not yet issued); then publish.
    __syncthreads();
    if (t < TSTEPS - 1 && tid == 0)
      __hip_atomic_store(flags + n, (u32)(t + 1), __ATOMIC_RELAXED, __HIP_MEMORY_SCOPE_AGENT);

    // fp32 outputs AFTER publish — their HBM ack is off the critical path
    size_t ob = (size_t)t * 65536 + erow * 1024 + j0;
    out[ob]     = hn0;
    out[ob + 1] = hn1;
    if (t == TSTEPS - 1) {
      out[33554432 + erow * 1024 + j0]     = hn0;   // h_last
      out[33554432 + erow * 1024 + j0 + 1] = hn1;
      out[33619968 + erow * 1024 + j0]     = cn0;   // c_last
      out[33619968 + erow * 1024 + j0 + 1] = cn1;
    }
  }
}

extern "C" void kernel_launch(void* const* d_in, const int* in_sizes, int n_in,
                              void* d_out, int out_size, void* d_ws, size_t ws_size,
                              hipStream_t stream) {
  const float* x  = (const float*)d_in[0];
  const float* h0 = (const float*)d_in[1];
  const float* c0 = (const float*)d_in[2];
  const float* Wf = (const float*)d_in[3];
  const float* bf = (const float*)d_in[4];
  const float* Wi = (const float*)d_in[5];
  const float* bi = (const float*)d_in[6];
  const float* Wc = (const float*)d_in[7];
  const float* bc = (const float*)d_in[8];
  const float* Wo = (const float*)d_in[9];
  const float* bo = (const float*)d_in[10];

  // workspace layout: wfrag 16MB | xbf 64MB | hb 256KB | flags/epochs 2KB
  if (ws_size < ((80u << 20) + (1u << 18) + 2048)) return;
  char* ws   = (char*)d_ws;
  u16* wfrag = (u16*)ws;
  u16* xbf   = (u16*)(ws + (16u << 20));
  u16* hb    = (u16*)(ws + (80u << 20));
  u32* flags = (u32*)(ws + (80u << 20) + (1u << 18));
  float* outp = (float*)d_out;

  hipMemsetAsync(flags, 0, 2048, stream);
  convert_x_kernel<<<2048, 256, 0, stream>>>(x, xbf, (long)512 * 64 * 1024);
  convert_h0_tiled<<<128, 256, 0, stream>>>(h0, hb);
  arrange_w_kernel<<<512, 256, 0, stream>>>(Wf, Wi, Wc, Wo, wfrag);

  void* args[] = {(void*)&xbf, (void*)&wfrag, (void*)&c0, (void*)&bf, (void*)&bi,
                  (void*)&bc, (void*)&bo, (void*)&hb, (void*)&outp, (void*)&flags};
  hipError_t e = hipLaunchCooperativeKernel((const void*)lstm_main_kernel, dim3(NWG + 1),
                                            dim3(256), args, 0, stream);
  if (e != hipSuccess) {
    // 129 WGs at 1 WG/CU on 256 CUs are trivially co-resident; plain launch is
    // a safe fallback so a silent cooperative-launch failure can't stub the run.
    lstm_main_kernel<<<dim3(NWG + 1), dim3(256), 0, stream>>>(xbf, wfrag, c0, bf, bi,
                                                              bc, bo, hb, outp, flags);
  }
}